// Round 8
// baseline (164.690 us; speedup 1.0000x reference)
//
#include <hip/hip_runtime.h>

// Problem constants
#define NB 16
#define NH 32
#define NKVH 8
#define NG 4            // H / KVH
#define ND 128
#define BLOCK 16
#define NUM_FETCH 256   // CACHE_LEN / BLOCK
#define NSPLIT 16
#define PAGES_PER_WG 16 // (CACHE_LEN/NSPLIT)/BLOCK
#define PAGES_PER_WAVE 4
#define PIECES 8        // 2 half-pages per page
#define PIECE_ROWS 8
#define PIECE_FLOATS (PIECE_ROWS * ND)   // 1024 floats = 4 KB

static constexpr float SCALE_LOG2E = 0.08838834764831845f * 1.4426950408889634f;

// ---------------------------------------------------------------------------
// Cache layout: reference reshape makes each 16-row page HEAD-MAJOR:
//   float offset of [page, kvh, i, d] = page*16384 + kvh*2048 + i*128 + d,
// fetch_slots[b][j] = page*16. Each (page, kvh) = contiguous 8 KB, 16 rows.
//
// R8: per-wave barrier-free pipeline. Wave w owns pages w*4..w*4+3 as 8
// half-page pieces; 2 LDS slots/wave; counted s_waitcnt vmcnt(8) so the next
// piece's 8 global_load_lds (8 KB) stay in flight through the compute phase
// (T3/T4: never drain vmcnt to 0 in the loop). lgkmcnt(0) before re-staging
// a slot guarantees its ds_reads retired (no LDS write race). No
// __syncthreads in the main loop. Softmax m=0; split partials sum directly.
// ---------------------------------------------------------------------------

__device__ __forceinline__ void gld_lds16(const float* g, float* l) {
    __builtin_amdgcn_global_load_lds(
        (const __attribute__((address_space(1))) void*)g,
        (__attribute__((address_space(3))) void*)l,
        16, 0, 0);
}

__global__ __launch_bounds__(256) void pa_main(
    const float* __restrict__ Q,
    const float* __restrict__ Kcache,
    const float* __restrict__ Vcache,
    const float* __restrict__ cosb,
    const float* __restrict__ sinb,
    const int*   __restrict__ fetch,
    float* __restrict__ accws,
    float* __restrict__ lws)
{
    const int wg    = blockIdx.x;
    const int split = wg & (NSPLIT - 1);
    const int kvh   = (wg >> 4) & (NKVH - 1);
    const int b     = wg >> 7;

    const int tid  = threadIdx.x;
    const int w    = tid >> 6;      // wave id 0..3
    const int lane = tid & 63;
    const int half = lane >> 5;
    const int l32  = lane & 31;
    const int d0   = l32 << 2;      // dims d0..d0+3

    const int* fb = fetch + b * NUM_FETCH + split * PAGES_PER_WG;

    // this wave's 4 page indices (uniform, constant-indexed)
    int pgv[PAGES_PER_WAVE];
    #pragma unroll
    for (int i = 0; i < PAGES_PER_WAVE; ++i)
        pgv[i] = __builtin_amdgcn_readfirstlane(fb[w * PAGES_PER_WAVE + i]);

    __shared__ float kbuf[4][2][PIECE_FLOATS];
    __shared__ float vbuf[4][2][PIECE_FLOATS];

    const size_t khead = (size_t)kvh * (BLOCK * ND);

    // stage piece p (page pgv[p>>1], rows (p&1)*8 .. +7) into slot s.
    // 8 x 1KB global_load_lds: no dest VGPRs, wave-uniform LDS base.
    auto stage = [&](int s, int p) {
        const size_t base = (size_t)pgv[p >> 1] * (NKVH * ND) + khead
                          + (size_t)(p & 1) * PIECE_FLOATS;
        const float* kg = Kcache + base + lane * 4;
        const float* vg = Vcache + base + lane * 4;
        #pragma unroll
        for (int i = 0; i < 4; ++i) {
            gld_lds16(kg + i * 256, &kbuf[w][s][i * 256]);
            gld_lds16(vg + i * 256, &vbuf[w][s][i * 256]);
        }
    };

    // RoPE'd, scaled Q for the 4 grouped heads (head h = g*NKVH + kvh)
    const float4 cs = *(const float4*)(cosb + b * ND + d0);
    const float4 sn = *(const float4*)(sinb + b * ND + d0);
    const float  sgn = (d0 < 64) ? -1.f : 1.f;
    const int    dp  = d0 ^ 64;
    float qv[NG][4];
    #pragma unroll
    for (int g = 0; g < NG; ++g) {
        const float* qp = Q + (size_t)(b * NH + g * NKVH + kvh) * ND;
        const float4 qa = *(const float4*)(qp + d0);
        const float4 qb = *(const float4*)(qp + dp);
        qv[g][0] = (qa.x * cs.x + sgn * qb.x * sn.x) * SCALE_LOG2E;
        qv[g][1] = (qa.y * cs.y + sgn * qb.y * sn.y) * SCALE_LOG2E;
        qv[g][2] = (qa.z * cs.z + sgn * qb.z * sn.z) * SCALE_LOG2E;
        qv[g][3] = (qa.w * cs.w + sgn * qb.w * sn.w) * SCALE_LOG2E;
    }

    float acc[NG][4] = {{0.f,0.f,0.f,0.f},{0.f,0.f,0.f,0.f},
                        {0.f,0.f,0.f,0.f},{0.f,0.f,0.f,0.f}};
    float lsum[NG] = {0.f, 0.f, 0.f, 0.f};

    // prologue: pieces 0,1 in flight (16 loads outstanding)
    stage(0, 0);
    stage(1, 1);

    #pragma unroll
    for (int j = 0; j < PIECES; ++j) {
        // piece j's 8 loads done; piece j+1's 8 remain outstanding
        if (j < PIECES - 1) asm volatile("s_waitcnt vmcnt(8)" ::: "memory");
        else                asm volatile("s_waitcnt vmcnt(0)" ::: "memory");
        __builtin_amdgcn_sched_barrier(0);

        // compute piece j from slot j&1; half h -> piece rows h*4..h*4+3
        {
            const float* kp = &kbuf[w][j & 1][half * 4 * ND + d0];
            const float* vp = &vbuf[w][j & 1][half * 4 * ND + d0];
            const float4 k0 = *(const float4*)(kp);
            const float4 k1 = *(const float4*)(kp + ND);
            const float4 k2 = *(const float4*)(kp + 2 * ND);
            const float4 k3 = *(const float4*)(kp + 3 * ND);
            const float4 v0 = *(const float4*)(vp);
            const float4 v1 = *(const float4*)(vp + ND);
            const float4 v2 = *(const float4*)(vp + 2 * ND);
            const float4 v3 = *(const float4*)(vp + 3 * ND);

            float s[4][NG];
            #pragma unroll
            for (int g = 0; g < NG; ++g) {
                s[0][g] = qv[g][0]*k0.x + qv[g][1]*k0.y + qv[g][2]*k0.z + qv[g][3]*k0.w;
                s[1][g] = qv[g][0]*k1.x + qv[g][1]*k1.y + qv[g][2]*k1.z + qv[g][3]*k1.w;
                s[2][g] = qv[g][0]*k2.x + qv[g][1]*k2.y + qv[g][2]*k2.z + qv[g][3]*k2.w;
                s[3][g] = qv[g][0]*k3.x + qv[g][1]*k3.y + qv[g][2]*k3.z + qv[g][3]*k3.w;
            }
            #pragma unroll
            for (int m = 16; m >= 1; m >>= 1)
                #pragma unroll
                for (int r = 0; r < 4; ++r)
                    #pragma unroll
                    for (int g = 0; g < NG; ++g)
                        s[r][g] += __shfl_xor(s[r][g], m, 64);
            #pragma unroll
            for (int g = 0; g < NG; ++g) {
                const float p0 = __builtin_amdgcn_exp2f(s[0][g]);
                const float p1 = __builtin_amdgcn_exp2f(s[1][g]);
                const float p2 = __builtin_amdgcn_exp2f(s[2][g]);
                const float p3 = __builtin_amdgcn_exp2f(s[3][g]);
                lsum[g] += (p0 + p1) + (p2 + p3);
                acc[g][0] += p0 * v0.x + p1 * v1.x + p2 * v2.x + p3 * v3.x;
                acc[g][1] += p0 * v0.y + p1 * v1.y + p2 * v2.y + p3 * v3.y;
                acc[g][2] += p0 * v0.z + p1 * v1.z + p2 * v2.z + p3 * v3.z;
                acc[g][3] += p0 * v0.w + p1 * v1.w + p2 * v2.w + p3 * v3.w;
            }
        }

        // ds_reads retired -> safe to overwrite this slot; then refill it
        asm volatile("s_waitcnt lgkmcnt(0)" ::: "memory");
        __builtin_amdgcn_sched_barrier(0);
        if (j + 2 < PIECES) stage(j & 1, j + 2);
    }

    // merge the two halves of each wave (different rows -> just add)
    #pragma unroll
    for (int g = 0; g < NG; ++g) {
        lsum[g] += __shfl_xor(lsum[g], 32, 64);
        #pragma unroll
        for (int j = 0; j < 4; ++j)
            acc[g][j] += __shfl_xor(acc[g][j], 32, 64);
    }

    // combine the 4 waves through LDS (waves' pages are disjoint -> add).
    __syncthreads();                       // all waves done with kbuf/vbuf
    float* s_acc = &kbuf[0][0][0];         // [4][NG][ND] = 2048 floats
    float* s_l   = &vbuf[0][0][0];         // [4][NG]
    if (half == 0) {
        #pragma unroll
        for (int g = 0; g < NG; ++g)
            *(float4*)&s_acc[(w * NG + g) * ND + d0] =
                make_float4(acc[g][0], acc[g][1], acc[g][2], acc[g][3]);
        if (l32 == 0) {
            #pragma unroll
            for (int g = 0; g < NG; ++g) s_l[w * NG + g] = lsum[g];
        }
    }
    __syncthreads();

    const size_t pslot = (size_t)(b * NKVH + kvh) * NSPLIT + split;
    for (int idx = tid; idx < NG * ND; idx += 256) {
        const int g = idx >> 7, d = idx & 127;
        accws[(pslot * NG + g) * ND + d] =
            s_acc[(0 * NG + g) * ND + d] + s_acc[(1 * NG + g) * ND + d] +
            s_acc[(2 * NG + g) * ND + d] + s_acc[(3 * NG + g) * ND + d];
    }
    if (tid < NG)
        lws[pslot * NG + tid] = s_l[0 * NG + tid] + s_l[1 * NG + tid]
                              + s_l[2 * NG + tid] + s_l[3 * NG + tid];
}

// ---------------------------------------------------------------------------
// Combine kernel: one block per (b, h). Sums the NSPLIT partials, adds the
// fresh token (RoPE'd K, raw V), divides by the softmax denominator.
// ---------------------------------------------------------------------------
__global__ __launch_bounds__(128) void pa_combine(
    const float* __restrict__ Q,
    const float* __restrict__ Knew,
    const float* __restrict__ Vnew,
    const float* __restrict__ cosb,
    const float* __restrict__ sinb,
    const float* __restrict__ accws,
    const float* __restrict__ lws,
    float* __restrict__ Y)
{
    const int bh  = blockIdx.x;
    const int b   = bh >> 5;            // / NH
    const int h   = bh & (NH - 1);
    const int kvh = h & (NKVH - 1);     // Qg reshape: h = g*KVH + kvh
    const int g   = h >> 3;
    const int d   = threadIdx.x;

    const float c   = cosb[b * ND + d];
    const float s   = sinb[b * ND + d];
    const float sgn = (d < 64) ? -1.f : 1.f;
    const int   dp  = d ^ 64;
    const float* qp = Q    + (size_t)(b * NH + h) * ND;
    const float* kp = Knew + (size_t)(b * NKVH + kvh) * ND;
    const float qr = qp[d] * c + sgn * qp[dp] * s;
    const float kr = kp[d] * c + sgn * kp[dp] * s;

    float prod = qr * kr;
    #pragma unroll
    for (int m = 32; m >= 1; m >>= 1) prod += __shfl_xor(prod, m, 64);
    __shared__ float red[2];
    if ((d & 63) == 0) red[d >> 6] = prod;
    __syncthreads();

    const float p = __builtin_amdgcn_exp2f((red[0] + red[1]) * SCALE_LOG2E);

    const size_t base = ((size_t)(b * NKVH + kvh) * NSPLIT) * NG + g;
    float acc = p * Vnew[(size_t)(b * NKVH + kvh) * ND + d];
    float lt  = p;
    #pragma unroll
    for (int sp = 0; sp < NSPLIT; ++sp) {
        acc += accws[(base + (size_t)sp * NG) * ND + d];
        lt  += lws[base + (size_t)sp * NG];
    }
    Y[(size_t)(b * NH + h) * ND + d] = acc / lt;
}

extern "C" void kernel_launch(void* const* d_in, const int* in_sizes, int n_in,
                              void* d_out, int out_size, void* d_ws, size_t ws_size,
                              hipStream_t stream)
{
    const float* Q    = (const float*)d_in[0];
    const float* K    = (const float*)d_in[1];
    const float* V    = (const float*)d_in[2];
    const float* Kc   = (const float*)d_in[3];
    const float* Vc   = (const float*)d_in[4];
    const float* cosb = (const float*)d_in[5];
    const float* sinb = (const float*)d_in[6];
    const int*   fetch = (const int*)d_in[7];
    // d_in[8] = save_slots: unused by the reference computation

    float* accws = (float*)d_ws;                                   // B*KVH*NSPLIT*G*D floats
    float* lws   = accws + (size_t)NB * NKVH * NSPLIT * NG * ND;   // B*KVH*NSPLIT*G floats
    float* Y     = (float*)d_out;

    pa_main<<<NB * NKVH * NSPLIT, 256, 0, stream>>>(Q, Kc, Vc, cosb, sinb, fetch, accws, lws);
    pa_combine<<<NB * NH, 128, 0, stream>>>(Q, K, V, cosb, sinb, accws, lws, Y);
}

// Round 9
// 140.375 us; speedup vs baseline: 1.1732x; 1.1732x over previous
//
#include <hip/hip_runtime.h>

// Problem constants
#define NB 16
#define NH 32
#define NKVH 8
#define NG 4            // H / KVH
#define ND 128
#define BLOCK 16
#define NUM_FETCH 256   // CACHE_LEN / BLOCK
#define NSPLIT 16
#define CHUNK 256       // CACHE_LEN / NSPLIT
#define ITERS 32        // CHUNK / (4 waves * 2 positions)

static constexpr float SCALE_LOG2E = 0.08838834764831845f * 1.4426950408889634f;

// ---------------------------------------------------------------------------
// Cache layout: reference reshapes (ROWS, KVH, D) -> (MAX_BLOCKS, KVH, BLOCK, D):
//   float offset of [page, kvh, i, d] = page*16384 + kvh*2048 + i*128 + d
// and fetch_slots[b][j] = page*16, so page*16384 = fetch_slots*1024.
//
// R9 = R2 (best real timing, 102.6 us) + unroll 4. Six structural variants
// (reg ping-pong, LDS dbuf, counted vmcnt) all tie within 15% real time:
// the kernel delivers ~5.7 TB/s of the 6.29 TB/s copy ceiling on the
// mandatory 537 MB --> near the delivered-BW roofline. This is the last
// bounded nudge (more MLP per wave, no regalloc risk).
// ---------------------------------------------------------------------------
__global__ __launch_bounds__(256, 4) void pa_main(
    const float* __restrict__ Q,
    const float* __restrict__ Kcache,
    const float* __restrict__ Vcache,
    const float* __restrict__ cosb,
    const float* __restrict__ sinb,
    const int*   __restrict__ fetch,
    float* __restrict__ accws,
    float* __restrict__ lws)
{
    const int wg    = blockIdx.x;
    const int split = wg & (NSPLIT - 1);
    const int kvh   = (wg >> 4) & (NKVH - 1);
    const int b     = wg >> 7;

    const int tid  = threadIdx.x;
    const int w    = tid >> 6;      // wave id 0..3
    const int lane = tid & 63;
    const int half = lane >> 5;     // which of the 2 positions
    const int l32  = lane & 31;
    const int d0   = l32 << 2;      // dims d0..d0+3

    // RoPE'd, scaled Q for the 4 grouped heads (head h = g*NKVH + kvh)
    const float4 cs = *(const float4*)(cosb + b * ND + d0);
    const float4 sn = *(const float4*)(sinb + b * ND + d0);
    const float  sgn = (d0 < 64) ? -1.f : 1.f;
    const int    dp  = d0 ^ 64;
    float qv[NG][4];
    #pragma unroll
    for (int g = 0; g < NG; ++g) {
        const float* qp = Q + (size_t)(b * NH + g * NKVH + kvh) * ND;
        const float4 qa = *(const float4*)(qp + d0);
        const float4 qb = *(const float4*)(qp + dp);
        qv[g][0] = (qa.x * cs.x + sgn * qb.x * sn.x) * SCALE_LOG2E;
        qv[g][1] = (qa.y * cs.y + sgn * qb.y * sn.y) * SCALE_LOG2E;
        qv[g][2] = (qa.z * cs.z + sgn * qb.z * sn.z) * SCALE_LOG2E;
        qv[g][3] = (qa.w * cs.w + sgn * qb.w * sn.w) * SCALE_LOG2E;
    }

    float acc[NG][4] = {{0.f,0.f,0.f,0.f},{0.f,0.f,0.f,0.f},
                        {0.f,0.f,0.f,0.f},{0.f,0.f,0.f,0.f}};
    float lsum[NG] = {0.f, 0.f, 0.f, 0.f};

    const int   pos0  = split * CHUNK + w * 2 + half;
    const int* __restrict__ fbase = fetch + b * NUM_FETCH;
    const size_t khead = (size_t)kvh * (BLOCK * ND);   // head-major within page
    const float* kb = Kcache + khead + d0;
    const float* vb = Vcache + khead + d0;

    #pragma unroll 4
    for (int it = 0; it < ITERS; ++it) {
        const int pos = pos0 + it * 8;
        // page float-offset = fetch_slots * (KVH*D); within page: i*D
        const size_t off = (size_t)fbase[pos >> 4] * (NKVH * ND)
                         + (size_t)(pos & (BLOCK - 1)) * ND;
        const float4 k4 = *(const float4*)(kb + off);
        const float4 v4 = *(const float4*)(vb + off);

        float s[NG];
        #pragma unroll
        for (int g = 0; g < NG; ++g)
            s[g] = qv[g][0]*k4.x + qv[g][1]*k4.y + qv[g][2]*k4.z + qv[g][3]*k4.w;

        // reduce over the 32 lanes of this half (xor masks <=16 stay in-half)
        #pragma unroll
        for (int m = 16; m >= 1; m >>= 1) {
            #pragma unroll
            for (int g = 0; g < NG; ++g)
                s[g] += __shfl_xor(s[g], m, 64);
        }

        #pragma unroll
        for (int g = 0; g < NG; ++g) {
            const float p = __builtin_amdgcn_exp2f(s[g]);
            lsum[g]   += p;
            acc[g][0] += p * v4.x;
            acc[g][1] += p * v4.y;
            acc[g][2] += p * v4.z;
            acc[g][3] += p * v4.w;
        }
    }

    // merge the two position-halves of each wave
    #pragma unroll
    for (int g = 0; g < NG; ++g) {
        lsum[g] += __shfl_xor(lsum[g], 32, 64);
        #pragma unroll
        for (int j = 0; j < 4; ++j)
            acc[g][j] += __shfl_xor(acc[g][j], 32, 64);
    }

    // combine the 4 waves through LDS, write split partial to workspace
    __shared__ float s_acc[4][NG][ND];
    __shared__ float s_l[4][NG];
    if (half == 0) {
        #pragma unroll
        for (int g = 0; g < NG; ++g)
            *(float4*)&s_acc[w][g][d0] =
                make_float4(acc[g][0], acc[g][1], acc[g][2], acc[g][3]);
        if (l32 == 0) {
            #pragma unroll
            for (int g = 0; g < NG; ++g) s_l[w][g] = lsum[g];
        }
    }
    __syncthreads();

    const size_t pslot = (size_t)(b * NKVH + kvh) * NSPLIT + split;
    for (int idx = tid; idx < NG * ND; idx += 256) {
        const int g = idx >> 7, d = idx & 127;
        accws[(pslot * NG + g) * ND + d] =
            s_acc[0][g][d] + s_acc[1][g][d] + s_acc[2][g][d] + s_acc[3][g][d];
    }
    if (tid < NG)
        lws[pslot * NG + tid] = s_l[0][tid] + s_l[1][tid] + s_l[2][tid] + s_l[3][tid];
}

// ---------------------------------------------------------------------------
// Combine kernel: one block per (b, h). Sums the NSPLIT partials, adds the
// fresh token (RoPE'd K, raw V), divides by the softmax denominator.
// ---------------------------------------------------------------------------
__global__ __launch_bounds__(128) void pa_combine(
    const float* __restrict__ Q,
    const float* __restrict__ Knew,
    const float* __restrict__ Vnew,
    const float* __restrict__ cosb,
    const float* __restrict__ sinb,
    const float* __restrict__ accws,
    const float* __restrict__ lws,
    float* __restrict__ Y)
{
    const int bh  = blockIdx.x;
    const int b   = bh >> 5;            // / NH
    const int h   = bh & (NH - 1);
    const int kvh = h & (NKVH - 1);     // Qg reshape: h = g*KVH + kvh
    const int g   = h >> 3;
    const int d   = threadIdx.x;

    const float c   = cosb[b * ND + d];
    const float s   = sinb[b * ND + d];
    const float sgn = (d < 64) ? -1.f : 1.f;
    const int   dp  = d ^ 64;
    const float* qp = Q    + (size_t)(b * NH + h) * ND;
    const float* kp = Knew + (size_t)(b * NKVH + kvh) * ND;
    const float qr = qp[d] * c + sgn * qp[dp] * s;
    const float kr = kp[d] * c + sgn * kp[dp] * s;

    float prod = qr * kr;
    #pragma unroll
    for (int m = 32; m >= 1; m >>= 1) prod += __shfl_xor(prod, m, 64);
    __shared__ float red[2];
    if ((d & 63) == 0) red[d >> 6] = prod;
    __syncthreads();

    const float p = __builtin_amdgcn_exp2f((red[0] + red[1]) * SCALE_LOG2E);

    const size_t base = ((size_t)(b * NKVH + kvh) * NSPLIT) * NG + g;
    float acc = p * Vnew[(size_t)(b * NKVH + kvh) * ND + d];
    float lt  = p;
    #pragma unroll
    for (int sp = 0; sp < NSPLIT; ++sp) {
        acc += accws[(base + (size_t)sp * NG) * ND + d];
        lt  += lws[base + (size_t)sp * NG];
    }
    Y[(size_t)(b * NH + h) * ND + d] = acc / lt;
}

extern "C" void kernel_launch(void* const* d_in, const int* in_sizes, int n_in,
                              void* d_out, int out_size, void* d_ws, size_t ws_size,
                              hipStream_t stream)
{
    const float* Q    = (const float*)d_in[0];
    const float* K    = (const float*)d_in[1];
    const float* V    = (const float*)d_in[2];
    const float* Kc   = (const float*)d_in[3];
    const float* Vc   = (const float*)d_in[4];
    const float* cosb = (const float*)d_in[5];
    const float* sinb = (const float*)d_in[6];
    const int*   fetch = (const int*)d_in[7];
    // d_in[8] = save_slots: unused by the reference computation

    float* accws = (float*)d_ws;                                   // B*KVH*NSPLIT*G*D floats
    float* lws   = accws + (size_t)NB * NKVH * NSPLIT * NG * ND;   // B*KVH*NSPLIT*G floats
    float* Y     = (float*)d_out;

    pa_main<<<NB * NKVH * NSPLIT, 256, 0, stream>>>(Q, Kc, Vc, cosb, sinb, fetch, accws, lws);
    pa_combine<<<NB * NH, 128, 0, stream>>>(Q, K, V, cosb, sinb, accws, lws, Y);
}

// Round 10
// 105.040 us; speedup vs baseline: 1.5679x; 1.3364x over previous
//
#include <hip/hip_runtime.h>

// Problem constants
#define NB 16
#define NH 32
#define NKVH 8
#define NG 4            // H / KVH
#define ND 128
#define BLOCK 16
#define NUM_FETCH 256   // CACHE_LEN / BLOCK
#define NSPLIT 16
#define CHUNK 256       // CACHE_LEN / NSPLIT
#define ITERS 32        // CHUNK / (4 waves * 2 positions)

static constexpr float SCALE_LOG2E = 0.08838834764831845f * 1.4426950408889634f;

// ---------------------------------------------------------------------------
// Cache layout: reference reshapes (ROWS, KVH, D) -> (MAX_BLOCKS, KVH, BLOCK, D):
//   float offset of [page, kvh, i, d] = page*16384 + kvh*2048 + i*128 + d
// and fetch_slots[b][j] = page*16, so page*16384 = fetch_slots*1024.
//
// R10 = R2 verbatim (best real timing: 102.6 us). Ceiling arithmetic:
// mandatory 537 MB delivered once at the 6.29 TB/s copy ceiling = 85 us
// pa_main floor; + combine + launches ~= 92-95 us total. R2 is within
// ~10% of that. Six structural variants (unroll-4, SGPR page hoist,
// batch-4 rows, register ping-pong, LDS double-buffer, counted-vmcnt
// pipeline) all regressed or tied: the kernel sits at the delivered-BW
// wall, FETCH=263 MB is the structural L3-hit max, no conflicts/spills.
// ---------------------------------------------------------------------------
__global__ __launch_bounds__(256, 4) void pa_main(
    const float* __restrict__ Q,
    const float* __restrict__ Kcache,
    const float* __restrict__ Vcache,
    const float* __restrict__ cosb,
    const float* __restrict__ sinb,
    const int*   __restrict__ fetch,
    float* __restrict__ accws,
    float* __restrict__ lws)
{
    const int wg    = blockIdx.x;
    const int split = wg & (NSPLIT - 1);
    const int kvh   = (wg >> 4) & (NKVH - 1);
    const int b     = wg >> 7;

    const int tid  = threadIdx.x;
    const int w    = tid >> 6;      // wave id 0..3
    const int lane = tid & 63;
    const int half = lane >> 5;     // which of the 2 positions
    const int l32  = lane & 31;
    const int d0   = l32 << 2;      // dims d0..d0+3

    // RoPE'd, scaled Q for the 4 grouped heads (head h = g*NKVH + kvh)
    const float4 cs = *(const float4*)(cosb + b * ND + d0);
    const float4 sn = *(const float4*)(sinb + b * ND + d0);
    const float  sgn = (d0 < 64) ? -1.f : 1.f;
    const int    dp  = d0 ^ 64;
    float qv[NG][4];
    #pragma unroll
    for (int g = 0; g < NG; ++g) {
        const float* qp = Q + (size_t)(b * NH + g * NKVH + kvh) * ND;
        const float4 qa = *(const float4*)(qp + d0);
        const float4 qb = *(const float4*)(qp + dp);
        qv[g][0] = (qa.x * cs.x + sgn * qb.x * sn.x) * SCALE_LOG2E;
        qv[g][1] = (qa.y * cs.y + sgn * qb.y * sn.y) * SCALE_LOG2E;
        qv[g][2] = (qa.z * cs.z + sgn * qb.z * sn.z) * SCALE_LOG2E;
        qv[g][3] = (qa.w * cs.w + sgn * qb.w * sn.w) * SCALE_LOG2E;
    }

    float acc[NG][4] = {{0.f,0.f,0.f,0.f},{0.f,0.f,0.f,0.f},
                        {0.f,0.f,0.f,0.f},{0.f,0.f,0.f,0.f}};
    float lsum[NG] = {0.f, 0.f, 0.f, 0.f};

    const int   pos0  = split * CHUNK + w * 2 + half;
    const int* __restrict__ fbase = fetch + b * NUM_FETCH;
    const size_t khead = (size_t)kvh * (BLOCK * ND);   // head-major within page
    const float* kb = Kcache + khead + d0;
    const float* vb = Vcache + khead + d0;

    #pragma unroll 2
    for (int it = 0; it < ITERS; ++it) {
        const int pos = pos0 + it * 8;
        // page float-offset = fetch_slots * (KVH*D); within page: i*D
        const size_t off = (size_t)fbase[pos >> 4] * (NKVH * ND)
                         + (size_t)(pos & (BLOCK - 1)) * ND;
        const float4 k4 = *(const float4*)(kb + off);
        const float4 v4 = *(const float4*)(vb + off);

        float s[NG];
        #pragma unroll
        for (int g = 0; g < NG; ++g)
            s[g] = qv[g][0]*k4.x + qv[g][1]*k4.y + qv[g][2]*k4.z + qv[g][3]*k4.w;

        // reduce over the 32 lanes of this half (xor masks <=16 stay in-half)
        #pragma unroll
        for (int m = 16; m >= 1; m >>= 1) {
            #pragma unroll
            for (int g = 0; g < NG; ++g)
                s[g] += __shfl_xor(s[g], m, 64);
        }

        #pragma unroll
        for (int g = 0; g < NG; ++g) {
            const float p = __builtin_amdgcn_exp2f(s[g]);
            lsum[g]   += p;
            acc[g][0] += p * v4.x;
            acc[g][1] += p * v4.y;
            acc[g][2] += p * v4.z;
            acc[g][3] += p * v4.w;
        }
    }

    // merge the two position-halves of each wave
    #pragma unroll
    for (int g = 0; g < NG; ++g) {
        lsum[g] += __shfl_xor(lsum[g], 32, 64);
        #pragma unroll
        for (int j = 0; j < 4; ++j)
            acc[g][j] += __shfl_xor(acc[g][j], 32, 64);
    }

    // combine the 4 waves through LDS, write split partial to workspace
    __shared__ float s_acc[4][NG][ND];
    __shared__ float s_l[4][NG];
    if (half == 0) {
        #pragma unroll
        for (int g = 0; g < NG; ++g)
            *(float4*)&s_acc[w][g][d0] =
                make_float4(acc[g][0], acc[g][1], acc[g][2], acc[g][3]);
        if (l32 == 0) {
            #pragma unroll
            for (int g = 0; g < NG; ++g) s_l[w][g] = lsum[g];
        }
    }
    __syncthreads();

    const size_t pslot = (size_t)(b * NKVH + kvh) * NSPLIT + split;
    for (int idx = tid; idx < NG * ND; idx += 256) {
        const int g = idx >> 7, d = idx & 127;
        accws[(pslot * NG + g) * ND + d] =
            s_acc[0][g][d] + s_acc[1][g][d] + s_acc[2][g][d] + s_acc[3][g][d];
    }
    if (tid < NG)
        lws[pslot * NG + tid] = s_l[0][tid] + s_l[1][tid] + s_l[2][tid] + s_l[3][tid];
}

// ---------------------------------------------------------------------------
// Combine kernel: one block per (b, h). Sums the NSPLIT partials, adds the
// fresh token (RoPE'd K, raw V), divides by the softmax denominator.
// ---------------------------------------------------------------------------
__global__ __launch_bounds__(128) void pa_combine(
    const float* __restrict__ Q,
    const float* __restrict__ Knew,
    const float* __restrict__ Vnew,
    const float* __restrict__ cosb,
    const float* __restrict__ sinb,
    const float* __restrict__ accws,
    const float* __restrict__ lws,
    float* __restrict__ Y)
{
    const int bh  = blockIdx.x;
    const int b   = bh >> 5;            // / NH
    const int h   = bh & (NH - 1);
    const int kvh = h & (NKVH - 1);     // Qg reshape: h = g*KVH + kvh
    const int g   = h >> 3;
    const int d   = threadIdx.x;

    const float c   = cosb[b * ND + d];
    const float s   = sinb[b * ND + d];
    const float sgn = (d < 64) ? -1.f : 1.f;
    const int   dp  = d ^ 64;
    const float* qp = Q    + (size_t)(b * NH + h) * ND;
    const float* kp = Knew + (size_t)(b * NKVH + kvh) * ND;
    const float qr = qp[d] * c + sgn * qp[dp] * s;
    const float kr = kp[d] * c + sgn * kp[dp] * s;

    float prod = qr * kr;
    #pragma unroll
    for (int m = 32; m >= 1; m >>= 1) prod += __shfl_xor(prod, m, 64);
    __shared__ float red[2];
    if ((d & 63) == 0) red[d >> 6] = prod;
    __syncthreads();

    const float p = __builtin_amdgcn_exp2f((red[0] + red[1]) * SCALE_LOG2E);

    const size_t base = ((size_t)(b * NKVH + kvh) * NSPLIT) * NG + g;
    float acc = p * Vnew[(size_t)(b * NKVH + kvh) * ND + d];
    float lt  = p;
    #pragma unroll
    for (int sp = 0; sp < NSPLIT; ++sp) {
        acc += accws[(base + (size_t)sp * NG) * ND + d];
        lt  += lws[base + (size_t)sp * NG];
    }
    Y[(size_t)(b * NH + h) * ND + d] = acc / lt;
}

extern "C" void kernel_launch(void* const* d_in, const int* in_sizes, int n_in,
                              void* d_out, int out_size, void* d_ws, size_t ws_size,
                              hipStream_t stream)
{
    const float* Q    = (const float*)d_in[0];
    const float* K    = (const float*)d_in[1];
    const float* V    = (const float*)d_in[2];
    const float* Kc   = (const float*)d_in[3];
    const float* Vc   = (const float*)d_in[4];
    const float* cosb = (const float*)d_in[5];
    const float* sinb = (const float*)d_in[6];
    const int*   fetch = (const int*)d_in[7];
    // d_in[8] = save_slots: unused by the reference computation

    float* accws = (float*)d_ws;                                   // B*KVH*NSPLIT*G*D floats
    float* lws   = accws + (size_t)NB * NKVH * NSPLIT * NG * ND;   // B*KVH*NSPLIT*G floats
    float* Y     = (float*)d_out;

    pa_main<<<NB * NKVH * NSPLIT, 256, 0, stream>>>(Q, Kc, Vc, cosb, sinb, fetch, accws, lws);
    pa_combine<<<NB * NH, 128, 0, stream>>>(Q, K, V, cosb, sinb, accws, lws, Y);
}